// Round 13
// baseline (215.476 us; speedup 1.0000x reference)
//
#include <hip/hip_runtime.h>
#include <hip/hip_bf16.h>

#define NUM_NODES 50000
#define DIM 64
#define NUM_EDGES 800000
#define NUM_GRAPHS 3
#define TOT_NODES (NUM_NODES * NUM_GRAPHS)      // 150000
#define EPS 1e-12f

#define NB2 391                                  // buckets per graph: dst>>7
#define TB2 (NB2 * NUM_GRAPHS)                   // 1173
#define PCAP2 2816                               // padded capacity (mean 2048, +17 sigma)
#define P3_CHUNK 4096
#define P3_BLOCKS ((NUM_EDGES + P3_CHUNK - 1) / P3_CHUNK)   // 196

typedef unsigned short ushort_t;
typedef unsigned int uint_t;
typedef unsigned int uint4v __attribute__((ext_vector_type(4)));       // 16 B
typedef unsigned short ushort8v __attribute__((ext_vector_type(8)));   // 16 B
typedef float f32x8 __attribute__((ext_vector_type(8)));

__device__ __forceinline__ ushort_t f2bf(float f) {
    uint_t x = __float_as_uint(f);
    uint_t r = (x + 0x7FFFu + ((x >> 16) & 1u)) >> 16;   // RNE
    return (ushort_t)r;
}

// unpack 8 bf16 (as uint4) into f32x8 — 1 VALU/elem; vector math -> v_pk_*
__device__ __forceinline__ f32x8 unpack8(uint4v w) {
    f32x8 r;
    r[0] = __uint_as_float(w[0] << 16);
    r[1] = __uint_as_float(w[0] & 0xFFFF0000u);
    r[2] = __uint_as_float(w[1] << 16);
    r[3] = __uint_as_float(w[1] & 0xFFFF0000u);
    r[4] = __uint_as_float(w[2] << 16);
    r[5] = __uint_as_float(w[2] & 0xFFFF0000u);
    r[6] = __uint_as_float(w[3] << 16);
    r[7] = __uint_as_float(w[3] & 0xFFFF0000u);
    return r;
}

// ---------------- partition edges into padded 128-node buckets (LDS-staged) ----------------
__global__ __launch_bounds__(512) void partition_kernel(
        const int* __restrict__ e0, const int* __restrict__ e1, const int* __restrict__ e2,
        int* __restrict__ gcnt, uint_t* __restrict__ part) {
    __shared__ uint_t recs[P3_CHUNK];        // 16 KB
    __shared__ int h[NB2], lstart[NB2], gbase[NB2], lcur[NB2];   // 6.3 KB
    __shared__ int wsum[8];

    int g = blockIdx.y;
    const int* ei = (g == 0) ? e0 : (g == 1) ? e1 : e2;
    const int* srcp = ei;
    const int* dstp = ei + NUM_EDGES;
    int base = blockIdx.x * P3_CHUNK;
    int n = min(P3_CHUNK, NUM_EDGES - base);
    int t = threadIdx.x;
    int wid = t >> 6, ln = t & 63;

    for (int i = t; i < NB2; i += 512) h[i] = 0;
    __syncthreads();
    for (int i = t; i < n; i += 512)
        atomicAdd(&h[dstp[base + i] >> 7], 1);
    __syncthreads();

    // wave-shfl exclusive scan over NB2 bins
    {
        int v = (t < NB2) ? h[t] : 0;
        int s = v;
        #pragma unroll
        for (int off = 1; off < 64; off <<= 1) {
            int u = __shfl_up(s, off, 64);
            if (ln >= off) s += u;
        }
        if (ln == 63) wsum[wid] = s;
        __syncthreads();
        int prefix = 0;
        #pragma unroll
        for (int w = 0; w < 8; ++w)
            if (w < wid) prefix += wsum[w];
        if (t < NB2) {
            int ex = prefix + s - v;
            lstart[t] = ex;
            lcur[t] = ex;
            gbase[t] = (v > 0) ? atomicAdd(&gcnt[g * NB2 + t], v) : 0;
        }
    }
    __syncthreads();

    // place records into LDS, bucket-grouped
    for (int i = t; i < n; i += 512) {
        int s = srcp[base + i];
        int d = dstp[base + i];
        int pos = atomicAdd(&lcur[d >> 7], 1);
        recs[pos] = ((uint_t)d << 16) | (uint_t)s;
    }
    __syncthreads();

    // stream out per bucket segment
    for (int i = t; i < n; i += 512) {
        uint_t r = recs[i];
        int b = r >> 23;                      // dst>>7
        int off = gbase[b] + (i - lstart[b]);
        if (off < PCAP2)
            part[(long)(g * NB2 + b) * PCAP2 + off] = r;
    }
}

// ---------------- per-bucket fine sort + dinv + fused l2norm/premult of this bucket's rows ----------------
__global__ __launch_bounds__(512) void bucket_sort_kernel(
        uint_t* __restrict__ part, const int* __restrict__ gcnt,
        const float* __restrict__ x,
        int* __restrict__ row_start, int* __restrict__ row_end, float* __restrict__ dinv,
        ushort_t* __restrict__ bufX) {
    __shared__ uint_t recs[PCAP2];           // 11.3 KB
    __shared__ ushort_t es_l[PCAP2];         // 5.6 KB
    __shared__ int hist[128], lcur[128];
    __shared__ float dinv_l[128];
    __shared__ int w0sum;

    int b = blockIdx.x;                       // 0..TB2-1
    int g = b / NB2;
    int bhi = b - g * NB2;
    long s0 = (long)b * PCAP2;
    int n = min(gcnt[b], PCAP2);
    int t = threadIdx.x;
    int ln = t & 63;

    if (t < 128) hist[t] = 0;
    __syncthreads();
    for (int i = t; i < n; i += 512) {
        uint_t r = part[s0 + i];
        recs[i] = r;
        atomicAdd(&hist[(r >> 16) & 127], 1);
    }
    __syncthreads();

    // wave-shfl exclusive scan over 128 bins
    int v = (t < 128) ? hist[t] : 0;
    int s = v;
    #pragma unroll
    for (int off = 1; off < 64; off <<= 1) {
        int u = __shfl_up(s, off, 64);
        if (ln >= off) s += u;
    }
    if (t == 63) w0sum = s;
    __syncthreads();
    if (t < 128) {
        int prefix = (t >= 64) ? w0sum : 0;
        int ex = prefix + s - v;
        lcur[t] = ex;
        float dv = (v > 0) ? rsqrtf((float)v) : 0.0f;
        dinv_l[t] = dv;
        int node = (bhi << 7) + t;
        if (node < NUM_NODES) {
            int k = g * NUM_NODES + node;
            int base = (int)(2 * s0);         // ushort index into (ushort*)part
            row_start[k] = base + ex;
            row_end[k]   = base + ex + v;
            dinv[k] = dv;
        }
    }
    __syncthreads();

    // fine-sort into LDS, coalesced copy-out
    for (int i = t; i < n; i += 512) {
        uint_t r = recs[i];
        int dl = (r >> 16) & 127;
        int pos = atomicAdd(&lcur[dl], 1);
        es_l[pos] = (ushort_t)(r & 0xFFFFu);
    }
    __syncthreads();
    uint_t* es_out = (uint_t*)((ushort_t*)part + 2 * s0);
    int nw = (n + 1) >> 1;
    const uint_t* es_lw = (const uint_t*)es_l;
    for (int i = t; i < nw; i += 512)
        es_out[i] = es_lw[i];

    // fused: l2-normalize this bucket's 128 x-rows, premultiply by dinv -> bufX[g]
    // 8 waves x 16 rows each; one wave per row per iteration (lane = dim)
    int wid = t >> 6;
    #pragma unroll
    for (int rr = 0; rr < 16; ++rr) {
        int r = wid * 16 + rr;
        int node = (bhi << 7) + r;
        if (node < NUM_NODES) {
            float xv = x[(long)node * DIM + ln];
            float ss = xv * xv;
            #pragma unroll
            for (int off = 32; off > 0; off >>= 1)
                ss += __shfl_xor(ss, off, 64);
            float nv = xv / fmaxf(sqrtf(ss), EPS);
            bufX[(long)(g * NUM_NODES + node) * DIM + ln] = f2bf(nv * dinv_l[r]);
        }
    }
}

// ---------------- layer 1, 2 rows/wave, unroll-4, grid (pair, g) ----------------
__global__ void conv1_kernel(const ushort_t* __restrict__ bufX,
                             const ushort_t* __restrict__ esort,
                             const int* __restrict__ row_start,
                             const int* __restrict__ row_end,
                             const float* __restrict__ dinv,
                             ushort_t* __restrict__ bufA) {
    int pair = blockIdx.x * (blockDim.x >> 6) + (threadIdx.x >> 6);
    int g = blockIdx.y;
    int lane = threadIdx.x & 63;
    int half = lane >> 5;         // 0: row 2p, 1: row 2p+1
    int sub  = (lane >> 3) & 3;   // edge slot within half
    int li   = lane & 7;          // dims [li*8, li*8+8)
    int row = pair * 2 + half;
    if (row >= NUM_NODES) return;

    int k = g * NUM_NODES + row;
    int start = row_start[k];
    int end   = row_end[k];
    const ushort_t* tbl = bufX + (long)g * NUM_NODES * DIM;

    f32x8 a = {0, 0, 0, 0, 0, 0, 0, 0};
    int i = start + sub;
    for (; i + 12 < end; i += 16) {
        int s0 = esort[i];
        int s1 = esort[i + 4];
        int s2 = esort[i + 8];
        int s3 = esort[i + 12];
        uint4v w0 = *(const uint4v*)(tbl + (long)s0 * DIM + li * 8);
        uint4v w1 = *(const uint4v*)(tbl + (long)s1 * DIM + li * 8);
        uint4v w2 = *(const uint4v*)(tbl + (long)s2 * DIM + li * 8);
        uint4v w3 = *(const uint4v*)(tbl + (long)s3 * DIM + li * 8);
        a += unpack8(w0);
        a += unpack8(w1);
        a += unpack8(w2);
        a += unpack8(w3);
    }
    for (; i + 4 < end; i += 8) {
        int s0 = esort[i];
        int s1 = esort[i + 4];
        uint4v w0 = *(const uint4v*)(tbl + (long)s0 * DIM + li * 8);
        uint4v w1 = *(const uint4v*)(tbl + (long)s1 * DIM + li * 8);
        a += unpack8(w0);
        a += unpack8(w1);
    }
    if (i < end) {
        int s = esort[i];
        uint4v w = *(const uint4v*)(tbl + (long)s * DIM + li * 8);
        a += unpack8(w);
    }
    // combine 4 subs within each 32-lane half (both rows share the instructions)
    #pragma unroll
    for (int off = 8; off < 32; off <<= 1) {
        #pragma unroll
        for (int j = 0; j < 8; ++j)
            a[j] += __shfl_xor(a[j], off, 64);
    }
    float dt = dinv[k];
    float scl = dt * dt;
    if (sub == 0) {
        ushort8v o;
        #pragma unroll
        for (int j = 0; j < 8; ++j) o[j] = f2bf(a[j] * scl);
        *(ushort8v*)(bufA + (long)k * DIM + li * 8) = o;
    }
}

// ---------------- layer 2, 2 rows/wave, unroll-4, in-wave g-loop + l2norm + blend ----------------
__global__ void conv2_finalize_kernel(const ushort_t* __restrict__ bufA,
                                      const ushort_t* __restrict__ esort,
                                      const int* __restrict__ row_start,
                                      const int* __restrict__ row_end,
                                      const float* __restrict__ alpha,
                                      float* __restrict__ out) {
    int pair = blockIdx.x * (blockDim.x >> 6) + (threadIdx.x >> 6);
    int lane = threadIdx.x & 63;
    int half = lane >> 5;
    int sub  = (lane >> 3) & 3;
    int li   = lane & 7;
    int row = pair * 2 + half;
    if (row >= NUM_NODES) return;

    // softmax(alpha) -> clip -> renormalize
    float al0 = alpha[0], al1 = alpha[1], al2 = alpha[2];
    float m = fmaxf(al0, fmaxf(al1, al2));
    float e0 = expf(al0 - m), e1 = expf(al1 - m), e2 = expf(al2 - m);
    float es = e0 + e1 + e2;
    float w0 = fmaxf(e0 / es, 1e-4f);
    float w1 = fmaxf(e1 / es, 1e-4f);
    float w2 = fmaxf(e2 / es, 1e-4f);
    float wsum = w0 + w1 + w2;

    f32x8 res = {0, 0, 0, 0, 0, 0, 0, 0};

    #pragma unroll
    for (int g = 0; g < NUM_GRAPHS; ++g) {
        int k = g * NUM_NODES + row;
        int start = row_start[k];
        int end   = row_end[k];
        const ushort_t* tbl = bufA + (long)g * NUM_NODES * DIM;

        f32x8 a = {0, 0, 0, 0, 0, 0, 0, 0};
        int i = start + sub;
        for (; i + 12 < end; i += 16) {
            int s0 = esort[i];
            int s1 = esort[i + 4];
            int s2 = esort[i + 8];
            int s3 = esort[i + 12];
            uint4v v0 = *(const uint4v*)(tbl + (long)s0 * DIM + li * 8);
            uint4v v1 = *(const uint4v*)(tbl + (long)s1 * DIM + li * 8);
            uint4v v2 = *(const uint4v*)(tbl + (long)s2 * DIM + li * 8);
            uint4v v3 = *(const uint4v*)(tbl + (long)s3 * DIM + li * 8);
            a += unpack8(v0);
            a += unpack8(v1);
            a += unpack8(v2);
            a += unpack8(v3);
        }
        for (; i + 4 < end; i += 8) {
            int s0 = esort[i];
            int s1 = esort[i + 4];
            uint4v v0 = *(const uint4v*)(tbl + (long)s0 * DIM + li * 8);
            uint4v v1 = *(const uint4v*)(tbl + (long)s1 * DIM + li * 8);
            a += unpack8(v0);
            a += unpack8(v1);
        }
        if (i < end) {
            int s = esort[i];
            uint4v w = *(const uint4v*)(tbl + (long)s * DIM + li * 8);
            a += unpack8(w);
        }
        #pragma unroll
        for (int off = 8; off < 32; off <<= 1) {
            #pragma unroll
            for (int j = 0; j < 8; ++j)
                a[j] += __shfl_xor(a[j], off, 64);
        }
        // row L2 norm within the 8-lane group (dinv_t row-scale cancels)
        float s = 0.0f;
        #pragma unroll
        for (int j = 0; j < 8; ++j) s += a[j] * a[j];
        #pragma unroll
        for (int off = 1; off < 8; off <<= 1)
            s += __shfl_xor(s, off, 64);
        float wg = ((g == 0) ? w0 : (g == 1) ? w1 : w2) / wsum;
        float scl = wg / fmaxf(sqrtf(s), EPS);
        res += a * scl;
    }

    if (sub == 0) {
        float* p = out + (long)row * DIM + li * 8;
        *(float4*)p = make_float4(res[0], res[1], res[2], res[3]);
        *(float4*)(p + 4) = make_float4(res[4], res[5], res[6], res[7]);
    }
}

extern "C" void kernel_launch(void* const* d_in, const int* in_sizes, int n_in,
                              void* d_out, int out_size, void* d_ws, size_t ws_size,
                              hipStream_t stream) {
    const float* x     = (const float*)d_in[0];
    const float* alpha = (const float*)d_in[1];
    const int* e0 = (const int*)d_in[2];
    const int* e1 = (const int*)d_in[3];
    const int* e2 = (const int*)d_in[4];
    float* out = (float*)d_out;

    // workspace layout (~53 MB)
    ushort_t* bufX = (ushort_t*)d_ws;                          // 3*50000*64 bf16 (19.2 MB)
    ushort_t* bufA = bufX + (long)TOT_NODES * DIM;             // 3*50000*64 bf16 (19.2 MB)
    float* dinv    = (float*)(bufA + (long)TOT_NODES * DIM);   // 150,000 f32
    int* row_start = (int*)(dinv + TOT_NODES);                 // 150,016
    int* row_end   = row_start + 150016;                       // 150,016
    int* gcnt      = row_end + 150016;                         // 1,176
    uint_t* part   = (uint_t*)(gcnt + 1176);                   // 1173*2816 u32   (13.2 MB)
    // esort lives IN-PLACE in part after bucket_sort

    const int pair_grid = ((NUM_NODES / 2) * 64 + 255) / 256;  // 2 rows/wave kernels

    // ---- partition into padded 128-node buckets ----
    hipMemsetAsync(gcnt, 0, TB2 * sizeof(int), stream);
    {
        dim3 grd(P3_BLOCKS, NUM_GRAPHS);
        partition_kernel<<<grd, 512, 0, stream>>>(e0, e1, e2, gcnt, part);
    }
    // ---- fine sort (esort in place) + row offsets + dinv + fused l2norm/premult ----
    bucket_sort_kernel<<<TB2, 512, 0, stream>>>(part, gcnt, x, row_start, row_end, dinv, bufX);

    const ushort_t* esort = (const ushort_t*)part;

    // ---- layer 1 (2 rows/wave, graph-major 2D grid) ----
    {
        dim3 grd(pair_grid, NUM_GRAPHS);
        conv1_kernel<<<grd, 256, 0, stream>>>(bufX, esort, row_start, row_end, dinv, bufA);
    }
    // ---- layer 2 + normalize + blend -> f32 out ----
    conv2_finalize_kernel<<<pair_grid, 256, 0, stream>>>(bufA, esort, row_start, row_end, alpha, out);
}